// Round 2
// baseline (39447.351 us; speedup 1.0000x reference)
//
#include <hip/hip_runtime.h>

typedef _Float16 f16;
typedef __attribute__((ext_vector_type(8))) _Float16 half8;
typedef __attribute__((ext_vector_type(4))) float f32x4;

#define B_   512
#define T_   256
#define TT_  320
#define KB0  33
#define KBR  64

__device__ __forceinline__ void gload16(const void* g, void* l) {
  __builtin_amdgcn_global_load_lds((const __attribute__((address_space(1))) void*)g,
                                   (__attribute__((address_space(3))) void*)l,
                                   16, 0, 0);
}

__device__ __forceinline__ float sigf(float x) {
  return __builtin_amdgcn_rcpf(1.f + __builtin_amdgcn_exp2f(-1.44269504f * x));
}
__device__ __forceinline__ float tanhf_(float x) {
  return 2.f * __builtin_amdgcn_rcpf(1.f + __builtin_amdgcn_exp2f(-2.88539008f * x)) - 1.f;
}

// fragment-ordered xh address: slab (k/32) of [512 rows x 32 k], tile layout [m/16][lane][8]
__device__ __forceinline__ int haddr(int k, int m) {
  return (k >> 5) * 16384 + (m >> 4) * 512 + ((m & 15) + ((k & 31) >> 3) * 16) * 8 + (k & 7);
}

// mode: 0 = layer0 (x-gen + out-init), 1 = mid layer, 2 = last layer (fused out-proj)
__global__ __launch_bounds__(512) void lstm_layer(
    const f16* __restrict__ Wt, const f16* __restrict__ xh_src,
    f16* __restrict__ xh_self, f16* __restrict__ xh_next,
    float* __restrict__ cst, const float* __restrict__ bias4,
    const float* __restrict__ input, const float* __restrict__ cov,
    float* __restrict__ outbuf, const float* __restrict__ blp,
    const float* __restrict__ Wl, int KB, int self_koff, int t, int mode)
{
  __shared__ f16 lds[2][6144];   // per buffer: A = 4096 halves (8KB), B = 2048 halves (4KB)
  const int tid = threadIdx.x;
  const int l = tid & 63, w = tid >> 6;
  const int nb = blockIdx.x & 63, mb = blockIdx.x >> 6;
  const int m0 = mb * 128, n0 = nb * 16;

  // init out[b][t] = bl before layer3's atomics (cross-launch ordering on stream)
  if (mode == 0 && nb == 0 && tid < 128) outbuf[(size_t)(m0 + tid) * TT_ + t] = blp[0];

  f32x4 acc[4];
  #pragma unroll
  for (int g = 0; g < 4; ++g) { acc[g][0] = 0.f; acc[g][1] = 0.f; acc[g][2] = 0.f; acc[g][3] = 0.f; }

  auto stageB = [&](int buf, int kb) {
    if (tid < 256)
      gload16(Wt + ((size_t)(nb * KB + kb)) * 2048 + tid * 8, &lds[buf][4096 + tid * 8]);
  };
  auto stageA = [&](int buf, int kb) {
    if (mode == 0 && kb == 0) {
      // generate x-columns (8 real + 24 zero pad) directly in fragment order
      int mf = tid >> 6, r = l & 15, kg = l >> 4;
      int brow = m0 + mf * 16 + r;
      half8 v;
      #pragma unroll
      for (int j = 0; j < 8; ++j) v[j] = (f16)0.f;
      if (kg == 0) {
        float x0 = (t < T_) ? input[brow * T_ + t] : outbuf[(size_t)brow * TT_ + (t - 1)];
        v[0] = (f16)x0;
        const float* cp = cov + ((size_t)brow * TT_ + t) * 7;
        #pragma unroll
        for (int j = 1; j < 8; ++j) v[j] = (f16)cp[j - 1];
      }
      *(half8*)&lds[buf][tid * 8] = v;
    } else if (t == 0 && kb >= (mode == 0 ? 1 : 32)) {
      // h(t=-1) == 0: self-initialize, never read stale workspace (no memset needed)
      half8 z;
      #pragma unroll
      for (int j = 0; j < 8; ++j) z[j] = (f16)0.f;
      *(half8*)&lds[buf][tid * 8] = z;
    } else {
      gload16(xh_src + (size_t)kb * 16384 + mb * 4096 + tid * 8, &lds[buf][tid * 8]);
    }
  };

  stageA(0, 0); stageB(0, 0);
  int cur = 0;
  for (int kb = 0; kb < KB; ++kb) {
    __syncthreads();                       // staging of buf[cur] complete (vmcnt drain at barrier)
    if (kb + 1 < KB) { stageA(cur ^ 1, kb + 1); stageB(cur ^ 1, kb + 1); }
    const half8* A  = (const half8*)&lds[cur][0];
    const half8* Bp = (const half8*)&lds[cur][4096];
    half8 a = A[w * 64 + l];               // wave w owns m-fragment w
    #pragma unroll
    for (int g = 0; g < 4; ++g)
      acc[g] = __builtin_amdgcn_mfma_f32_16x16x32_f16(a, Bp[g * 64 + l], acc[g], 0, 0, 0);
    __syncthreads();                       // all reads of buf[cur] done before it is restaged
    cur ^= 1;
  }

  // epilogue: lane l holds gates for rows rowb..rowb+3, col n0+(l&15)
  const int col = n0 + (l & 15);
  const int rowb = m0 + w * 16 + (l >> 4) * 4;
  const float bi  = bias4[col];
  const float bff = bias4[1024 + col];
  const float bgg = bias4[2048 + col];
  const float bo  = bias4[3072 + col];
  const float wl  = (mode == 2) ? Wl[col] : 0.f;
  #pragma unroll
  for (int r = 0; r < 4; ++r) {
    const int row = rowb + r;
    float gi = acc[0][r] + bi;
    float gf = acc[1][r] + bff;
    float gg = acc[2][r] + bgg;
    float go = acc[3][r] + bo;
    float* cp = cst + (size_t)row * 1024 + col;
    float cold = (t == 0) ? 0.f : *cp;     // c(t=-1) == 0: no stale workspace read
    float cn = sigf(gf) * cold + sigf(gi) * tanhf_(gg);
    float h  = sigf(go) * tanhf_(cn);
    *cp = cn;
    f16 hh = (f16)h;
    xh_self[haddr(self_koff + col, row)] = hh;       // h(t) for this layer's next step
    if (mode != 2) {
      xh_next[haddr(col, row)] = hh;                 // x-part for next layer, this step
    } else {
      float val = h * wl;                            // fused out-projection partial
      val += __shfl_xor(val, 1);
      val += __shfl_xor(val, 2);
      val += __shfl_xor(val, 4);
      val += __shfl_xor(val, 8);
      if ((l & 15) == 0) atomicAdd(outbuf + (size_t)row * TT_ + t, val);
    }
  }
}

__global__ void pack_weights(const float* __restrict__ Wih0, const float* __restrict__ Whh0,
                             const float* __restrict__ Wihr, const float* __restrict__ Whhr,
                             f16* __restrict__ Wt0, f16* __restrict__ Wt1,
                             f16* __restrict__ Wt2, f16* __restrict__ Wt3)
{
  const int layer = blockIdx.y;
  const size_t e = (size_t)blockIdx.x * 256 + threadIdx.x;
  const int KB = layer ? KBR : KB0;
  if (e >= (size_t)64 * KB * 2048) return;
  const int panel = (int)(e >> 11), win = (int)(e & 2047);
  const int g = win >> 9, lane = (win >> 3) & 63, j = win & 7;
  const int nb = panel / KB, kb = panel - nb * KB;
  const int n = nb * 16 + (lane & 15);
  const int k = kb * 32 + (lane >> 4) * 8 + j;
  const int jr = g * 1024 + n;                       // row in [4H][*] weight (gate-major)
  float v;
  if (layer == 0) {
    if (k < 8)       v = Wih0[jr * 8 + k];
    else if (k < 32) v = 0.f;
    else             v = Whh0[(size_t)jr * 1024 + (k - 32)];
  } else {
    const size_t base = (size_t)(layer - 1) * 4096 * 1024 + (size_t)jr * 1024;
    v = (k < 1024) ? Wihr[base + k] : Whhr[base + (k - 1024)];
  }
  f16 hv = (f16)v;
  if      (layer == 0) Wt0[e] = hv;
  else if (layer == 1) Wt1[e] = hv;
  else if (layer == 2) Wt2[e] = hv;
  else                 Wt3[e] = hv;
}

__global__ void pack_bias(const float* __restrict__ bih0, const float* __restrict__ bhh0,
                          const float* __restrict__ bihr, const float* __restrict__ bhhr,
                          float* __restrict__ bias)
{
  const int idx = blockIdx.x * 256 + threadIdx.x;    // 16384 = 4 layers x 4096
  const int lyr = idx >> 12, j = idx & 4095;
  bias[idx] = (lyr == 0) ? (bih0[j] + bhh0[j])
                         : (bihr[(lyr - 1) * 4096 + j] + bhhr[(lyr - 1) * 4096 + j]);
}

extern "C" void kernel_launch(void* const* d_in, const int* in_sizes, int n_in,
                              void* d_out, int out_size, void* d_ws, size_t ws_size,
                              hipStream_t stream)
{
  const float* input = (const float*)d_in[0];
  const float* cov   = (const float*)d_in[1];
  const float* Wih0  = (const float*)d_in[2];
  const float* Whh0  = (const float*)d_in[3];
  const float* bih0  = (const float*)d_in[4];
  const float* bhh0  = (const float*)d_in[5];
  const float* Wihr  = (const float*)d_in[6];
  const float* Whhr  = (const float*)d_in[7];
  const float* bihr  = (const float*)d_in[8];
  const float* bhhr  = (const float*)d_in[9];
  const float* Wl    = (const float*)d_in[10];
  const float* blp   = (const float*)d_in[11];
  float* out = (float*)d_out;
  char* ws = (char*)d_ws;

  // workspace layout (bytes):
  //   xh0[2] @ 0        (2 x 1,081,344)   ping-pong fragment-ordered A buffers
  //   xh1[2] @ 2162688  (2 x 2,097,152)
  //   xh2[2] @ 6356992  (2 x 2,097,152)
  //   xh3[2] @ 10551296 (2 x 2,097,152)
  //   c      @ 14745600 (4 x 2,097,152)   fp32 cell state
  //   bias   @ 23134208 (65,536)
  //   Wt0    @ 23199744 (8,650,752)       f16 fragment-packed weights
  //   Wt1    @ 31850496 (16,777,216)
  //   Wt2    @ 48627712 (16,777,216)
  //   Wt3    @ 65404928 (16,777,216)      total 82,182,144
  // All state (xh, c) is self-initialized at t==0 inside lstm_layer; no memset,
  // so every call is independent of prior d_ws/d_out contents (graph-replay safe).
  const size_t XH0 = 1081344, XHR = 2097152;
  f16* xh0[2] = { (f16*)(ws),            (f16*)(ws + XH0) };
  f16* xh1[2] = { (f16*)(ws + 2162688),  (f16*)(ws + 2162688 + XHR) };
  f16* xh2[2] = { (f16*)(ws + 6356992),  (f16*)(ws + 6356992 + XHR) };
  f16* xh3[2] = { (f16*)(ws + 10551296), (f16*)(ws + 10551296 + XHR) };
  float* cbase = (float*)(ws + 14745600);
  float* bias  = (float*)(ws + 23134208);
  f16* Wt0 = (f16*)(ws + 23199744);
  f16* Wt1 = (f16*)(ws + 31850496);
  f16* Wt2 = (f16*)(ws + 48627712);
  f16* Wt3 = (f16*)(ws + 65404928);

  pack_weights<<<dim3(32768, 4), 256, 0, stream>>>(Wih0, Whh0, Wihr, Whhr, Wt0, Wt1, Wt2, Wt3);
  pack_bias<<<64, 256, 0, stream>>>(bih0, bhh0, bihr, bhhr, bias);

  for (int t = 0; t < TT_; ++t) {
    const int p = t & 1, q = p ^ 1;
    lstm_layer<<<256, 512, 0, stream>>>(Wt0, xh0[p], xh0[q], xh1[p], cbase, bias,
                                        input, cov, out, blp, Wl, KB0, 32, t, 0);
    lstm_layer<<<256, 512, 0, stream>>>(Wt1, xh1[p], xh1[q], xh2[p], cbase + 524288, bias + 4096,
                                        input, cov, out, blp, Wl, KBR, 1024, t, 1);
    lstm_layer<<<256, 512, 0, stream>>>(Wt2, xh2[p], xh2[q], xh3[p], cbase + 1048576, bias + 8192,
                                        input, cov, out, blp, Wl, KBR, 1024, t, 2 - 1);
    lstm_layer<<<256, 512, 0, stream>>>(Wt3, xh3[p], xh3[q], nullptr, cbase + 1572864, bias + 12288,
                                        input, cov, out, blp, Wl, KBR, 1024, t, 2);
  }
}

// Round 3
// 24033.437 us; speedup vs baseline: 1.6414x; 1.6414x over previous
//
#include <hip/hip_runtime.h>

typedef _Float16 f16;
typedef __attribute__((ext_vector_type(8))) _Float16 half8;
typedef __attribute__((ext_vector_type(4))) float f32x4;

#define B_   512
#define T_   256
#define TT_  320
#define KB0  33
#define KBR  64
#define NBUF 6     // 6 x 12KB = 72KB LDS, prefetch depth 5

__device__ __forceinline__ void gload16(const void* g, void* l) {
  __builtin_amdgcn_global_load_lds((const __attribute__((address_space(1))) void*)g,
                                   (__attribute__((address_space(3))) void*)l,
                                   16, 0, 0);
}

__device__ __forceinline__ float sigf(float x) {
  return __builtin_amdgcn_rcpf(1.f + __builtin_amdgcn_exp2f(-1.44269504f * x));
}
__device__ __forceinline__ float tanhf_(float x) {
  return 2.f * __builtin_amdgcn_rcpf(1.f + __builtin_amdgcn_exp2f(-2.88539008f * x)) - 1.f;
}

// fragment-ordered xh address: slab (k/32) of [512 rows x 32 k], tile layout [m/16][lane][8]
__device__ __forceinline__ int haddr(int k, int m) {
  return (k >> 5) * 16384 + (m >> 4) * 512 + ((m & 15) + ((k & 31) >> 3) * 16) * 8 + (k & 7);
}

// counted wait + raw barrier, fused in ONE asm so nothing schedules between them.
// lgkmcnt(0) before s_barrier: my ds_reads/ds_writes retired => next iter's DMA
// into the recycled buffer can't race a still-queued read (buffer-reuse hazard).
#define WAITBAR(vm) asm volatile("s_waitcnt vmcnt(" #vm ") lgkmcnt(0)\n\ts_barrier" ::: "memory")

// mode: 0 = layer0 (x-gen + out-init), 1 = mid layer, 2 = last layer (fused out-proj)
__global__ __launch_bounds__(512) void lstm_layer(
    const f16* __restrict__ Wt, const f16* __restrict__ xh_src,
    f16* __restrict__ xh_self, f16* __restrict__ xh_next,
    float* __restrict__ cst, const float* __restrict__ bias4,
    const float* __restrict__ input, const float* __restrict__ cov,
    float* __restrict__ outbuf, const float* __restrict__ blp,
    const float* __restrict__ Wl, int KB, int self_koff, int t, int mode)
{
  __shared__ f16 lds[NBUF][6144];   // per buffer: A = 4096 halves (8KB), B = 2048 halves (4KB)
  const int tid = threadIdx.x;
  const int l = tid & 63, w = tid >> 6;
  const int nb = blockIdx.x & 63, mb = blockIdx.x >> 6;
  const int m0 = mb * 128, n0 = nb * 16;

  // init out[b][t] = bl before layer3's atomics (cross-launch ordering on stream)
  if (mode == 0 && nb == 0 && tid < 128) outbuf[(size_t)(m0 + tid) * TT_ + t] = blp[0];

  f32x4 acc[4];
  #pragma unroll
  for (int g = 0; g < 4; ++g) { acc[g][0] = 0.f; acc[g][1] = 0.f; acc[g][2] = 0.f; acc[g][3] = 0.f; }

  auto stageB = [&](int buf, int kb) {
    if (tid < 256)
      gload16(Wt + ((size_t)(nb * KB + kb)) * 2048 + tid * 8, &lds[buf][4096 + tid * 8]);
  };
  auto stageA = [&](int buf, int kb) {
    if (mode == 0 && kb == 0) {
      // generate x-columns (8 real + 24 zero pad) directly in fragment order (ds_write)
      int mf = tid >> 6, r = l & 15, kg = l >> 4;
      int brow = m0 + mf * 16 + r;
      half8 v;
      #pragma unroll
      for (int j = 0; j < 8; ++j) v[j] = (f16)0.f;
      if (kg == 0) {
        float x0 = (t < T_) ? input[brow * T_ + t] : outbuf[(size_t)brow * TT_ + (t - 1)];
        v[0] = (f16)x0;
        const float* cp = cov + ((size_t)brow * TT_ + t) * 7;
        #pragma unroll
        for (int j = 1; j < 8; ++j) v[j] = (f16)cp[j - 1];
      }
      *(half8*)&lds[buf][tid * 8] = v;
    } else if (t == 0 && kb >= (mode == 0 ? 1 : 32)) {
      // h(t=-1) == 0: self-initialize, never read stale workspace (legacy path only)
      half8 z;
      #pragma unroll
      for (int j = 0; j < 8; ++j) z[j] = (f16)0.f;
      *(half8*)&lds[buf][tid * 8] = z;
    } else {
      gload16(xh_src + (size_t)kb * 16384 + mb * 4096 + tid * 8, &lds[buf][tid * 8]);
    }
  };

  if (t == 0) {
    // ---- legacy 2-buffer __syncthreads loop (mixed ds_write/gload staging breaks
    // vmcnt bookkeeping; 1 of 320 steps, perf-irrelevant) ----
    stageA(0, 0); stageB(0, 0);
    int cur = 0;
    for (int kb = 0; kb < KB; ++kb) {
      __syncthreads();
      if (kb + 1 < KB) { stageA(cur ^ 1, kb + 1); stageB(cur ^ 1, kb + 1); }
      const half8* A  = (const half8*)&lds[cur][0];
      const half8* Bp = (const half8*)&lds[cur][4096];
      half8 a = A[w * 64 + l];
      #pragma unroll
      for (int g = 0; g < 4; ++g)
        acc[g] = __builtin_amdgcn_mfma_f32_16x16x32_f16(a, Bp[g * 64 + l], acc[g], 0, 0, 0);
      __syncthreads();
      cur ^= 1;
    }
  } else {
    // ---- pipelined path: 6 buffers, prefetch depth 5, counted vmcnt, raw barriers.
    // Per-stage vmem loads per lane: waves 0-3 (tid<256): A+B = 2; waves 4-7: A = 1.
    #pragma unroll
    for (int i = 0; i < 5; ++i) { stageA(i, i); stageB(i, i); }
    int rb = 0;                       // buffer holding K-step kb
    for (int kb = 0; kb < KB; ++kb) {
      int inflight = KB - 1 - kb; if (inflight > 4) inflight = 4;  // stages beyond kb in flight
      if (w < 4) {
        switch (inflight) {
          case 4:  WAITBAR(8); break;
          case 3:  WAITBAR(6); break;
          case 2:  WAITBAR(4); break;
          case 1:  WAITBAR(2); break;
          default: WAITBAR(0); break;
        }
      } else {
        switch (inflight) {
          case 4:  WAITBAR(4); break;
          case 3:  WAITBAR(3); break;
          case 2:  WAITBAR(2); break;
          case 1:  WAITBAR(1); break;
          default: WAITBAR(0); break;
        }
      }
      const half8* A  = (const half8*)&lds[rb][0];
      const half8* Bp = (const half8*)&lds[rb][4096];
      half8 a  = A[w * 64 + l];                  // plain ds_reads: issued before the
      half8 b0 = Bp[l];                          // stage below (may alias same LDS array)
      half8 b1 = Bp[64 + l];
      half8 b2 = Bp[128 + l];
      half8 b3 = Bp[192 + l];
      if (kb + 5 < KB) {                         // recycle buf[(kb-1)%6]; safe: all waves
        int sb = rb + 5 - ((rb >= 1) ? 6 : 0);   // passed the barrier with lgkmcnt(0)
        stageA(sb, kb + 5); stageB(sb, kb + 5);
      }
      acc[0] = __builtin_amdgcn_mfma_f32_16x16x32_f16(a, b0, acc[0], 0, 0, 0);
      acc[1] = __builtin_amdgcn_mfma_f32_16x16x32_f16(a, b1, acc[1], 0, 0, 0);
      acc[2] = __builtin_amdgcn_mfma_f32_16x16x32_f16(a, b2, acc[2], 0, 0, 0);
      acc[3] = __builtin_amdgcn_mfma_f32_16x16x32_f16(a, b3, acc[3], 0, 0, 0);
      rb = (rb == NBUF - 1) ? 0 : rb + 1;
    }
  }

  // epilogue: lane l holds gates for rows rowb..rowb+3, col n0+(l&15)
  const int col = n0 + (l & 15);
  const int rowb = m0 + w * 16 + (l >> 4) * 4;
  const float bi  = bias4[col];
  const float bff = bias4[1024 + col];
  const float bgg = bias4[2048 + col];
  const float bo  = bias4[3072 + col];
  const float wl  = (mode == 2) ? Wl[col] : 0.f;
  #pragma unroll
  for (int r = 0; r < 4; ++r) {
    const int row = rowb + r;
    float gi = acc[0][r] + bi;
    float gf = acc[1][r] + bff;
    float gg = acc[2][r] + bgg;
    float go = acc[3][r] + bo;
    float* cp = cst + (size_t)row * 1024 + col;
    float cold = (t == 0) ? 0.f : *cp;     // c(t=-1) == 0: no stale workspace read
    float cn = sigf(gf) * cold + sigf(gi) * tanhf_(gg);
    float h  = sigf(go) * tanhf_(cn);
    *cp = cn;
    f16 hh = (f16)h;
    xh_self[haddr(self_koff + col, row)] = hh;       // h(t) for this layer's next step
    if (mode != 2) {
      xh_next[haddr(col, row)] = hh;                 // x-part for next layer, this step
    } else {
      float val = h * wl;                            // fused out-projection partial
      val += __shfl_xor(val, 1);
      val += __shfl_xor(val, 2);
      val += __shfl_xor(val, 4);
      val += __shfl_xor(val, 8);
      if ((l & 15) == 0) atomicAdd(outbuf + (size_t)row * TT_ + t, val);
    }
  }
}

__global__ void pack_weights(const float* __restrict__ Wih0, const float* __restrict__ Whh0,
                             const float* __restrict__ Wihr, const float* __restrict__ Whhr,
                             f16* __restrict__ Wt0, f16* __restrict__ Wt1,
                             f16* __restrict__ Wt2, f16* __restrict__ Wt3)
{
  const int layer = blockIdx.y;
  const size_t e = (size_t)blockIdx.x * 256 + threadIdx.x;
  const int KB = layer ? KBR : KB0;
  if (e >= (size_t)64 * KB * 2048) return;
  const int panel = (int)(e >> 11), win = (int)(e & 2047);
  const int g = win >> 9, lane = (win >> 3) & 63, j = win & 7;
  const int nb = panel / KB, kb = panel - nb * KB;
  const int n = nb * 16 + (lane & 15);
  const int k = kb * 32 + (lane >> 4) * 8 + j;
  const int jr = g * 1024 + n;                       // row in [4H][*] weight (gate-major)
  float v;
  if (layer == 0) {
    if (k < 8)       v = Wih0[jr * 8 + k];
    else if (k < 32) v = 0.f;
    else             v = Whh0[(size_t)jr * 1024 + (k - 32)];
  } else {
    const size_t base = (size_t)(layer - 1) * 4096 * 1024 + (size_t)jr * 1024;
    v = (k < 1024) ? Wihr[base + k] : Whhr[base + (k - 1024)];
  }
  f16 hv = (f16)v;
  if      (layer == 0) Wt0[e] = hv;
  else if (layer == 1) Wt1[e] = hv;
  else if (layer == 2) Wt2[e] = hv;
  else                 Wt3[e] = hv;
}

__global__ void pack_bias(const float* __restrict__ bih0, const float* __restrict__ bhh0,
                          const float* __restrict__ bihr, const float* __restrict__ bhhr,
                          float* __restrict__ bias)
{
  const int idx = blockIdx.x * 256 + threadIdx.x;    // 16384 = 4 layers x 4096
  const int lyr = idx >> 12, j = idx & 4095;
  bias[idx] = (lyr == 0) ? (bih0[j] + bhh0[j])
                         : (bihr[(lyr - 1) * 4096 + j] + bhhr[(lyr - 1) * 4096 + j]);
}

extern "C" void kernel_launch(void* const* d_in, const int* in_sizes, int n_in,
                              void* d_out, int out_size, void* d_ws, size_t ws_size,
                              hipStream_t stream)
{
  const float* input = (const float*)d_in[0];
  const float* cov   = (const float*)d_in[1];
  const float* Wih0  = (const float*)d_in[2];
  const float* Whh0  = (const float*)d_in[3];
  const float* bih0  = (const float*)d_in[4];
  const float* bhh0  = (const float*)d_in[5];
  const float* Wihr  = (const float*)d_in[6];
  const float* Whhr  = (const float*)d_in[7];
  const float* bihr  = (const float*)d_in[8];
  const float* bhhr  = (const float*)d_in[9];
  const float* Wl    = (const float*)d_in[10];
  const float* blp   = (const float*)d_in[11];
  float* out = (float*)d_out;
  char* ws = (char*)d_ws;

  // workspace layout (bytes):
  //   xh0[2] @ 0        (2 x 1,081,344)   ping-pong fragment-ordered A buffers
  //   xh1[2] @ 2162688  (2 x 2,097,152)
  //   xh2[2] @ 6356992  (2 x 2,097,152)
  //   xh3[2] @ 10551296 (2 x 2,097,152)
  //   c      @ 14745600 (4 x 2,097,152)   fp32 cell state
  //   bias   @ 23134208 (65,536)
  //   Wt0    @ 23199744 (8,650,752)       f16 fragment-packed weights
  //   Wt1    @ 31850496 (16,777,216)
  //   Wt2    @ 48627712 (16,777,216)
  //   Wt3    @ 65404928 (16,777,216)      total 82,182,144
  // All state (xh, c) is self-initialized at t==0 inside lstm_layer; no memset,
  // so every call is independent of prior d_ws/d_out contents (graph-replay safe).
  const size_t XH0 = 1081344, XHR = 2097152;
  f16* xh0[2] = { (f16*)(ws),            (f16*)(ws + XH0) };
  f16* xh1[2] = { (f16*)(ws + 2162688),  (f16*)(ws + 2162688 + XHR) };
  f16* xh2[2] = { (f16*)(ws + 6356992),  (f16*)(ws + 6356992 + XHR) };
  f16* xh3[2] = { (f16*)(ws + 10551296), (f16*)(ws + 10551296 + XHR) };
  float* cbase = (float*)(ws + 14745600);
  float* bias  = (float*)(ws + 23134208);
  f16* Wt0 = (f16*)(ws + 23199744);
  f16* Wt1 = (f16*)(ws + 31850496);
  f16* Wt2 = (f16*)(ws + 48627712);
  f16* Wt3 = (f16*)(ws + 65404928);

  pack_weights<<<dim3(32768, 4), 256, 0, stream>>>(Wih0, Whh0, Wihr, Whhr, Wt0, Wt1, Wt2, Wt3);
  pack_bias<<<64, 256, 0, stream>>>(bih0, bhh0, bihr, bhhr, bias);

  for (int t = 0; t < TT_; ++t) {
    const int p = t & 1, q = p ^ 1;
    lstm_layer<<<256, 512, 0, stream>>>(Wt0, xh0[p], xh0[q], xh1[p], cbase, bias,
                                        input, cov, out, blp, Wl, KB0, 32, t, 0);
    lstm_layer<<<256, 512, 0, stream>>>(Wt1, xh1[p], xh1[q], xh2[p], cbase + 524288, bias + 4096,
                                        input, cov, out, blp, Wl, KBR, 1024, t, 1);
    lstm_layer<<<256, 512, 0, stream>>>(Wt2, xh2[p], xh2[q], xh3[p], cbase + 1048576, bias + 8192,
                                        input, cov, out, blp, Wl, KBR, 1024, t, 1);
    lstm_layer<<<256, 512, 0, stream>>>(Wt3, xh3[p], xh3[q], nullptr, cbase + 1572864, bias + 12288,
                                        input, cov, out, blp, Wl, KBR, 1024, t, 2);
  }
}

// Round 4
// 21033.615 us; speedup vs baseline: 1.8754x; 1.1426x over previous
//
#include <hip/hip_runtime.h>

typedef _Float16 f16;
typedef __attribute__((ext_vector_type(8))) _Float16 half8;
typedef __attribute__((ext_vector_type(4))) float f32x4;

#define B_   512
#define T_   256
#define TT_  320
#define KB0  33
#define KBR  64
#define NSLOT 12   // ring of 3 rounds x 4 slabs; 12 x 12KB = 144KB LDS

__device__ __forceinline__ void gload16(const void* g, void* l) {
  __builtin_amdgcn_global_load_lds((const __attribute__((address_space(1))) void*)g,
                                   (__attribute__((address_space(3))) void*)l,
                                   16, 0, 0);
}

__device__ __forceinline__ float sigf(float x) {
  return __builtin_amdgcn_rcpf(1.f + __builtin_amdgcn_exp2f(-1.44269504f * x));
}
__device__ __forceinline__ float tanhf_(float x) {
  return 2.f * __builtin_amdgcn_rcpf(1.f + __builtin_amdgcn_exp2f(-2.88539008f * x)) - 1.f;
}

// fragment-ordered xh address: slab (k/32) of [512 rows x 32 k], tile layout [m/16][lane][8]
__device__ __forceinline__ int haddr(int k, int m) {
  return (k >> 5) * 16384 + (m >> 4) * 512 + ((m & 15) + ((k & 31) >> 3) * 16) * 8 + (k & 7);
}

// counted wait + raw barrier fused in ONE asm so nothing schedules between them.
// lgkmcnt(0) before s_barrier: my ds_reads retired => post-barrier DMA into a
// recycled slot can't race a still-queued read (buffer-reuse hazard).
#define WAITBAR(vm) asm volatile("s_waitcnt vmcnt(" #vm ") lgkmcnt(0)\n\ts_barrier" ::: "memory")

// mode: 0 = layer0 (x-gen + out-init), 1 = mid layer, 2 = last layer (fused out-proj)
__global__ __launch_bounds__(512) void lstm_layer(
    const f16* __restrict__ Wt, const f16* __restrict__ xh_src,
    f16* __restrict__ xh_self, f16* __restrict__ xh_next,
    float* __restrict__ cst, const float* __restrict__ bias4,
    const float* __restrict__ input, const float* __restrict__ cov,
    float* __restrict__ outbuf, const float* __restrict__ blp,
    const float* __restrict__ Wl, int KB, int self_koff, int t, int mode)
{
  __shared__ f16 lds[NSLOT][6144];  // per slab: A = 4096 halves (8KB), B = 2048 halves (4KB)
  const int tid = threadIdx.x;
  const int l = tid & 63, w = tid >> 6;
  const int mg = w & 1, kg = w >> 1;        // split-K wave grid: 2 m-groups x 4 k-groups
  const int nb = blockIdx.x & 63, mb = blockIdx.x >> 6;
  const int m0 = mb * 128, n0 = nb * 16;

  // init out[b][t] = bl before layer3's atomics (cross-launch ordering on stream)
  if (mode == 0 && nb == 0 && tid < 128) outbuf[(size_t)(m0 + tid) * TT_ + t] = blp[0];

  auto stage_slab = [&](int slot, int kb) {
    // A-half (8KB): all 512 threads, 16B each
    if (mode == 0 && kb == 0) {
      // generate x-columns (8 real + 24 zero pad) directly in fragment order (ds_write, 0 vm)
      int mf = tid >> 6, r = l & 15, kgrp = l >> 4;
      int brow = m0 + mf * 16 + r;
      half8 v;
      #pragma unroll
      for (int j = 0; j < 8; ++j) v[j] = (f16)0.f;
      if (kgrp == 0) {
        float x0 = (t < T_) ? input[brow * T_ + t] : outbuf[(size_t)brow * TT_ + (t - 1)];
        v[0] = (f16)x0;
        const float* cp = cov + ((size_t)brow * TT_ + t) * 7;
        #pragma unroll
        for (int j = 1; j < 8; ++j) v[j] = (f16)cp[j - 1];
      }
      *(half8*)&lds[slot][tid * 8] = v;
    } else if (t == 0 && kb >= (mode == 0 ? 1 : 32)) {
      // h(t=-1) == 0: self-initialize, never read stale workspace (legacy t==0 path only)
      half8 z;
      #pragma unroll
      for (int j = 0; j < 8; ++j) z[j] = (f16)0.f;
      *(half8*)&lds[slot][tid * 8] = z;
    } else {
      gload16(xh_src + (size_t)kb * 16384 + mb * 4096 + tid * 8, &lds[slot][tid * 8]);
    }
    // B-half (4KB): threads 0..255 (waves 0-3), 16B each
    if (tid < 256)
      gload16(Wt + ((size_t)(nb * KB + kb)) * 2048 + tid * 8, &lds[slot][4096 + tid * 8]);
  };
  auto stage_round = [&](int r) {           // 4 slabs; clamp => constant vm counts (8 / 4)
    int base = (r % 3) * 4;
    #pragma unroll
    for (int j = 0; j < 4; ++j) {
      int kb = r * 4 + j;
      if (kb >= KB) kb = KB - 1;            // phantom dup of last slab (mode0 tail only)
      stage_slab(base + j, kb);
    }
  };

  f32x4 facc[4];                            // final per-wave gate accs (wave w = m-frag w)
  #pragma unroll
  for (int g = 0; g < 4; ++g) { facc[g][0]=0.f; facc[g][1]=0.f; facc[g][2]=0.f; facc[g][3]=0.f; }

  if (t == 0) {
    // ---- legacy 2-slot __syncthreads loop (ds_write staging breaks vmcnt counts;
    // 1 of 320 steps, perf-irrelevant). (1,4) tiling: wave w owns m-frag w, 4 gates.
    stage_slab(0, 0);
    int cur = 0;
    for (int kb = 0; kb < KB; ++kb) {
      __syncthreads();
      if (kb + 1 < KB) stage_slab(cur ^ 1, kb + 1);
      const half8* A  = (const half8*)&lds[cur][0];
      const half8* Bp = (const half8*)&lds[cur][4096];
      half8 a = A[w * 64 + l];
      #pragma unroll
      for (int g = 0; g < 4; ++g)
        facc[g] = __builtin_amdgcn_mfma_f32_16x16x32_f16(a, Bp[g * 64 + l], facc[g], 0, 0, 0);
      __syncthreads();
      cur ^= 1;
    }
  } else {
    // ---- split-K pipelined path: wave (mg,kg) accumulates 4 m-frags x 4 gates over
    // slabs kb = 4i+kg. Ring of 3 rounds; stage r_{i+2} after round-i barrier (its slots
    // held r_{i-1}, whose reads retired at this barrier via lgkmcnt(0)).
    f32x4 acc[4][4];
    #pragma unroll
    for (int m = 0; m < 4; ++m)
      #pragma unroll
      for (int g = 0; g < 4; ++g) { acc[m][g][0]=0.f; acc[m][g][1]=0.f; acc[m][g][2]=0.f; acc[m][g][3]=0.f; }

    const int R = (KB + 3) >> 2;
    stage_round(0); stage_round(1);
    for (int i = 0; i < R; ++i) {
      // entering round i: r_i and r_{i+1} outstanding; wait until only r_{i+1} remains.
      if (i < R - 1) { if (w < 4) WAITBAR(8); else WAITBAR(4); }
      else           { WAITBAR(0); }
      const int kb = i * 4 + kg;
      const int slot = (i % 3) * 4 + kg;
      const half8* A  = (const half8*)&lds[slot][0];
      const half8* Bp = (const half8*)&lds[slot][4096];
      const bool live = (kb < KB);          // wave-uniform (mode0 last round, kg>0)
      half8 a0, a1, a2, a3, b0, b1, b2, b3;
      if (live) {
        a0 = A[(mg * 4 + 0) * 64 + l];
        a1 = A[(mg * 4 + 1) * 64 + l];
        a2 = A[(mg * 4 + 2) * 64 + l];
        a3 = A[(mg * 4 + 3) * 64 + l];
        b0 = Bp[l]; b1 = Bp[64 + l]; b2 = Bp[128 + l]; b3 = Bp[192 + l];
      }
      if (i + 2 < R) stage_round(i + 2);
      if (live) {
        acc[0][0] = __builtin_amdgcn_mfma_f32_16x16x32_f16(a0, b0, acc[0][0], 0, 0, 0);
        acc[0][1] = __builtin_amdgcn_mfma_f32_16x16x32_f16(a0, b1, acc[0][1], 0, 0, 0);
        acc[0][2] = __builtin_amdgcn_mfma_f32_16x16x32_f16(a0, b2, acc[0][2], 0, 0, 0);
        acc[0][3] = __builtin_amdgcn_mfma_f32_16x16x32_f16(a0, b3, acc[0][3], 0, 0, 0);
        acc[1][0] = __builtin_amdgcn_mfma_f32_16x16x32_f16(a1, b0, acc[1][0], 0, 0, 0);
        acc[1][1] = __builtin_amdgcn_mfma_f32_16x16x32_f16(a1, b1, acc[1][1], 0, 0, 0);
        acc[1][2] = __builtin_amdgcn_mfma_f32_16x16x32_f16(a1, b2, acc[1][2], 0, 0, 0);
        acc[1][3] = __builtin_amdgcn_mfma_f32_16x16x32_f16(a1, b3, acc[1][3], 0, 0, 0);
        acc[2][0] = __builtin_amdgcn_mfma_f32_16x16x32_f16(a2, b0, acc[2][0], 0, 0, 0);
        acc[2][1] = __builtin_amdgcn_mfma_f32_16x16x32_f16(a2, b1, acc[2][1], 0, 0, 0);
        acc[2][2] = __builtin_amdgcn_mfma_f32_16x16x32_f16(a2, b2, acc[2][2], 0, 0, 0);
        acc[2][3] = __builtin_amdgcn_mfma_f32_16x16x32_f16(a2, b3, acc[2][3], 0, 0, 0);
        acc[3][0] = __builtin_amdgcn_mfma_f32_16x16x32_f16(a3, b0, acc[3][0], 0, 0, 0);
        acc[3][1] = __builtin_amdgcn_mfma_f32_16x16x32_f16(a3, b1, acc[3][1], 0, 0, 0);
        acc[3][2] = __builtin_amdgcn_mfma_f32_16x16x32_f16(a3, b2, acc[3][2], 0, 0, 0);
        acc[3][3] = __builtin_amdgcn_mfma_f32_16x16x32_f16(a3, b3, acc[3][3], 0, 0, 0);
      }
    }

    // ---- split-K reduction via LDS (vmcnt==0 here; slabs dead). 8x16KB = 128KB.
    __syncthreads();                        // all slab ds_reads done before overwrite
    float* red = (float*)&lds[0][0];
    #pragma unroll
    for (int m = 0; m < 4; ++m)
      #pragma unroll
      for (int g = 0; g < 4; ++g)
        *(f32x4*)&red[w * 4096 + (m * 4 + g) * 256 + l * 4] = acc[m][g];
    __syncthreads();
    const int mgw = w >> 2, mlw = w & 3;    // final wave w owns m-frag w = mgw*4+mlw
    #pragma unroll
    for (int kg2 = 0; kg2 < 4; ++kg2) {
      const int wsrc = kg2 * 2 + mgw;
      #pragma unroll
      for (int g = 0; g < 4; ++g) {
        f32x4 p = *(const f32x4*)&red[wsrc * 4096 + (mlw * 4 + g) * 256 + l * 4];
        facc[g][0] += p[0]; facc[g][1] += p[1]; facc[g][2] += p[2]; facc[g][3] += p[3];
      }
    }
  }

  // epilogue: lane l holds gates for rows rowb..rowb+3, col n0+(l&15)
  const int col = n0 + (l & 15);
  const int rowb = m0 + w * 16 + (l >> 4) * 4;
  const float bi  = bias4[col];
  const float bff = bias4[1024 + col];
  const float bgg = bias4[2048 + col];
  const float bo  = bias4[3072 + col];
  const float wl  = (mode == 2) ? Wl[col] : 0.f;
  #pragma unroll
  for (int r = 0; r < 4; ++r) {
    const int row = rowb + r;
    float gi = facc[0][r] + bi;
    float gf = facc[1][r] + bff;
    float gg = facc[2][r] + bgg;
    float go = facc[3][r] + bo;
    float* cp = cst + (size_t)row * 1024 + col;
    float cold = (t == 0) ? 0.f : *cp;     // c(t=-1) == 0: no stale workspace read
    float cn = sigf(gf) * cold + sigf(gi) * tanhf_(gg);
    float h  = sigf(go) * tanhf_(cn);
    *cp = cn;
    f16 hh = (f16)h;
    xh_self[haddr(self_koff + col, row)] = hh;       // h(t) for this layer's next step
    if (mode != 2) {
      xh_next[haddr(col, row)] = hh;                 // x-part for next layer, this step
    } else {
      float val = h * wl;                            // fused out-projection partial
      val += __shfl_xor(val, 1);
      val += __shfl_xor(val, 2);
      val += __shfl_xor(val, 4);
      val += __shfl_xor(val, 8);
      if ((l & 15) == 0) atomicAdd(outbuf + (size_t)row * TT_ + t, val);
    }
  }
}

__global__ void pack_weights(const float* __restrict__ Wih0, const float* __restrict__ Whh0,
                             const float* __restrict__ Wihr, const float* __restrict__ Whhr,
                             f16* __restrict__ Wt0, f16* __restrict__ Wt1,
                             f16* __restrict__ Wt2, f16* __restrict__ Wt3)
{
  const int layer = blockIdx.y;
  const size_t e = (size_t)blockIdx.x * 256 + threadIdx.x;
  const int KB = layer ? KBR : KB0;
  if (e >= (size_t)64 * KB * 2048) return;
  const int panel = (int)(e >> 11), win = (int)(e & 2047);
  const int g = win >> 9, lane = (win >> 3) & 63, j = win & 7;
  const int nb = panel / KB, kb = panel - nb * KB;
  const int n = nb * 16 + (lane & 15);
  const int k = kb * 32 + (lane >> 4) * 8 + j;
  const int jr = g * 1024 + n;                       // row in [4H][*] weight (gate-major)
  float v;
  if (layer == 0) {
    if (k < 8)       v = Wih0[jr * 8 + k];
    else if (k < 32) v = 0.f;
    else             v = Whh0[(size_t)jr * 1024 + (k - 32)];
  } else {
    const size_t base = (size_t)(layer - 1) * 4096 * 1024 + (size_t)jr * 1024;
    v = (k < 1024) ? Wihr[base + k] : Whhr[base + (k - 1024)];
  }
  f16 hv = (f16)v;
  if      (layer == 0) Wt0[e] = hv;
  else if (layer == 1) Wt1[e] = hv;
  else if (layer == 2) Wt2[e] = hv;
  else                 Wt3[e] = hv;
}

__global__ void pack_bias(const float* __restrict__ bih0, const float* __restrict__ bhh0,
                          const float* __restrict__ bihr, const float* __restrict__ bhhr,
                          float* __restrict__ bias)
{
  const int idx = blockIdx.x * 256 + threadIdx.x;    // 16384 = 4 layers x 4096
  const int lyr = idx >> 12, j = idx & 4095;
  bias[idx] = (lyr == 0) ? (bih0[j] + bhh0[j])
                         : (bihr[(lyr - 1) * 4096 + j] + bhhr[(lyr - 1) * 4096 + j]);
}

extern "C" void kernel_launch(void* const* d_in, const int* in_sizes, int n_in,
                              void* d_out, int out_size, void* d_ws, size_t ws_size,
                              hipStream_t stream)
{
  const float* input = (const float*)d_in[0];
  const float* cov   = (const float*)d_in[1];
  const float* Wih0  = (const float*)d_in[2];
  const float* Whh0  = (const float*)d_in[3];
  const float* bih0  = (const float*)d_in[4];
  const float* bhh0  = (const float*)d_in[5];
  const float* Wihr  = (const float*)d_in[6];
  const float* Whhr  = (const float*)d_in[7];
  const float* bihr  = (const float*)d_in[8];
  const float* bhhr  = (const float*)d_in[9];
  const float* Wl    = (const float*)d_in[10];
  const float* blp   = (const float*)d_in[11];
  float* out = (float*)d_out;
  char* ws = (char*)d_ws;

  // workspace layout (bytes):
  //   xh0[2] @ 0        (2 x 1,081,344)   ping-pong fragment-ordered A buffers
  //   xh1[2] @ 2162688  (2 x 2,097,152)
  //   xh2[2] @ 6356992  (2 x 2,097,152)
  //   xh3[2] @ 10551296 (2 x 2,097,152)
  //   c      @ 14745600 (4 x 2,097,152)   fp32 cell state
  //   bias   @ 23134208 (65,536)
  //   Wt0    @ 23199744 (8,650,752)       f16 fragment-packed weights
  //   Wt1    @ 31850496 (16,777,216)
  //   Wt2    @ 48627712 (16,777,216)
  //   Wt3    @ 65404928 (16,777,216)      total 82,182,144
  // All state (xh, c) is self-initialized at t==0 inside lstm_layer; no memset,
  // so every call is independent of prior d_ws/d_out contents (graph-replay safe).
  const size_t XH0 = 1081344, XHR = 2097152;
  f16* xh0[2] = { (f16*)(ws),            (f16*)(ws + XH0) };
  f16* xh1[2] = { (f16*)(ws + 2162688),  (f16*)(ws + 2162688 + XHR) };
  f16* xh2[2] = { (f16*)(ws + 6356992),  (f16*)(ws + 6356992 + XHR) };
  f16* xh3[2] = { (f16*)(ws + 10551296), (f16*)(ws + 10551296 + XHR) };
  float* cbase = (float*)(ws + 14745600);
  float* bias  = (float*)(ws + 23134208);
  f16* Wt0 = (f16*)(ws + 23199744);
  f16* Wt1 = (f16*)(ws + 31850496);
  f16* Wt2 = (f16*)(ws + 48627712);
  f16* Wt3 = (f16*)(ws + 65404928);

  pack_weights<<<dim3(32768, 4), 256, 0, stream>>>(Wih0, Whh0, Wihr, Whhr, Wt0, Wt1, Wt2, Wt3);
  pack_bias<<<64, 256, 0, stream>>>(bih0, bhh0, bihr, bhhr, bias);

  for (int t = 0; t < TT_; ++t) {
    const int p = t & 1, q = p ^ 1;
    lstm_layer<<<256, 512, 0, stream>>>(Wt0, xh0[p], xh0[q], xh1[p], cbase, bias,
                                        input, cov, out, blp, Wl, KB0, 32, t, 0);
    lstm_layer<<<256, 512, 0, stream>>>(Wt1, xh1[p], xh1[q], xh2[p], cbase + 524288, bias + 4096,
                                        input, cov, out, blp, Wl, KBR, 1024, t, 1);
    lstm_layer<<<256, 512, 0, stream>>>(Wt2, xh2[p], xh2[q], xh3[p], cbase + 1048576, bias + 8192,
                                        input, cov, out, blp, Wl, KBR, 1024, t, 1);
    lstm_layer<<<256, 512, 0, stream>>>(Wt3, xh3[p], xh3[q], nullptr, cbase + 1572864, bias + 12288,
                                        input, cov, out, blp, Wl, KBR, 1024, t, 2);
  }
}